// Round 8
// baseline (204.054 us; speedup 1.0000x reference)
//
#include <hip/hip_runtime.h>

#define BS 32
#define NE 512
#define DMODEL 512
#define HEADS 8
#define EMB 64
#define FFH 256
#define MTOK (BS*NE)   // 16384

typedef unsigned short u16;
typedef short v8s __attribute__((ext_vector_type(8)));
typedef float f32x4 __attribute__((ext_vector_type(4)));
typedef u16 u16x4 __attribute__((ext_vector_type(4)));

#define GLOAD16(G, L) \
  __builtin_amdgcn_global_load_lds((const __attribute__((address_space(1))) unsigned int*)(G), \
      (__attribute__((address_space(3))) unsigned int*)(L), 16, 0, 0)

static __device__ __forceinline__ unsigned cvt_pk_bf16(float lo, float hi) {
    unsigned r;
    asm("v_cvt_pk_bf16_f32 %0, %1, %2" : "=v"(r) : "v"(lo), "v"(hi));
    return r;
}

static __device__ __forceinline__ u16 f2bf_bits(float f) {
    unsigned u = __float_as_uint(f);
    u += 0x7fffu + ((u >> 16) & 1u);   // round-to-nearest-even
    return (u16)(u >> 16);
}
static __device__ __forceinline__ float bf2f_bits(u16 h) {
    return __uint_as_float(((unsigned)h) << 16);
}

// ---------------- fused conversion kernel ----------------
// idx < 2097152: x f32 -> bf16 (float4 granules). Above: 5 weights -> transposed bf16.
__global__ __launch_bounds__(256) void cvt_all_kernel(
    const float* __restrict__ x, u16* __restrict__ xb,
    const float* __restrict__ Wq, const float* __restrict__ Wk, const float* __restrict__ Wv,
    const float* __restrict__ W1, const float* __restrict__ W2,
    u16* __restrict__ WqkvT, u16* __restrict__ W1T, u16* __restrict__ W2T)
{
    int idx = blockIdx.x * 256 + threadIdx.x;
    if (idx < 2097152) {                      // x: MTOK*DMODEL/4 float4s
        float4 v = ((const float4*)x)[idx];
        u16x4 o = { f2bf_bits(v.x), f2bf_bits(v.y), f2bf_bits(v.z), f2bf_bits(v.w) };
        ((u16x4*)xb)[idx] = o;
        return;
    }
    int widx = idx - 2097152;                 // 0 .. 1048575
    if (widx < 786432) {
        int w = widx >> 18, rem = widx & 262143;
        int k = rem >> 9, n = rem & 511;
        const float* src = (w == 0) ? Wq : (w == 1) ? Wk : Wv;
        WqkvT[(size_t)(w*512 + n)*512 + k] = f2bf_bits(src[rem]);
    } else if (widx < 917504) {
        int rem = widx - 786432;              // W1: [512][256]
        int k = rem >> 8, n = rem & 255;
        W1T[n*512 + k] = f2bf_bits(W1[rem]);
    } else if (widx < 1048576) {
        int rem = widx - 917504;              // W2: [256][512]
        int k = rem >> 9, n = rem & 511;
        W2T[n*256 + k] = f2bf_bits(W2[rem]);
    }
}

// ---------------- GEMM: C = A(MxKC) @ BT(NxKC)^T + bias ----------------
// 128xBN tile, 4 waves (wave tile 64 x BN/2), BK=64, single-buffer LDS,
// 2 barriers/K-step. Vectorized epilogues (uint2 stores).
//  EPI 0: swapped acc (C^T = mfma(B,A)) -> row-major store
//  EPI 2: same + relu
//  EPI 4: fused QKV. col-blocks in Q/K range: swapped acc + Q pre-scale;
//         col-blocks in V range (bRow0>=1024): normal acc -> vT packing.
template<int EPI, int KC, int BN>
__global__ __launch_bounds__(256, 2) void gemm_kernel(
    const u16* __restrict__ A, const u16* __restrict__ BT,
    const float* __restrict__ bsQ, const float* __restrict__ bsK, const float* __restrict__ bsV,
    u16* __restrict__ oQ, u16* __restrict__ oK, u16* __restrict__ oVT,
    int N, int NC)
{
    __shared__ u16 Ab[128*64];
    __shared__ u16 Bb[BN*64];
    const int tid = threadIdx.x;
    const int wave = tid >> 6, lane = tid & 63;
    const int lr = lane & 15, lg = lane >> 4, lr7 = lr & 7;
    const int id = blockIdx.x;
    const int rr = id & 7, qq = id >> 3;
    const int gk = qq / NC, colBlk = qq - gk*NC;
    const int rowBlk = gk*8 + rr;
    const int aRow0 = rowBlk*128, bRow0 = colBlk*BN;
    const int wlo = (wave >> 1)*64, wco = (wave & 1)*(BN/2);
    const int srow = tid >> 3, schunk = tid & 7;
    const int soff = ((schunk ^ (srow & 7)) << 3);
    const bool isV = (EPI == 4) && (bRow0 >= 1024);   // V col-range of fused QKV
    const bool swapacc = !isV;

    auto stage = [&](int k0) {
        #pragma unroll
        for (int i = 0; i < 4; ++i)
            GLOAD16(A  + (size_t)(aRow0 + i*32 + srow)*KC + k0 + soff, (char*)Ab + i*4096 + wave*1024);
        #pragma unroll
        for (int i = 0; i < BN/32; ++i)
            GLOAD16(BT + (size_t)(bRow0 + i*32 + srow)*KC + k0 + soff, (char*)Bb + i*4096 + wave*1024);
    };

    f32x4 acc[4][BN/32] = {};
    constexpr int NT = KC / 64;
    #pragma unroll
    for (int t = 0; t < NT; ++t) {
        stage(t*64);
        __syncthreads();                     // drains vmcnt: tile landed, all waves
        #pragma unroll
        for (int kk = 0; kk < 2; ++kk) {
            v8s af[4], bf[BN/32];
            #pragma unroll
            for (int i = 0; i < 4; ++i)
                af[i] = *(const v8s*)((const char*)Ab + (wlo + i*16 + lr)*128 + ((((kk<<2)|lg) ^ lr7) << 4));
            #pragma unroll
            for (int j = 0; j < BN/32; ++j)
                bf[j] = *(const v8s*)((const char*)Bb + (wco + j*16 + lr)*128 + ((((kk<<2)|lg) ^ lr7) << 4));
            #pragma unroll
            for (int i = 0; i < 4; ++i)
                #pragma unroll
                for (int j = 0; j < BN/32; ++j) {
                    if (swapacc)
                        acc[i][j] = __builtin_amdgcn_mfma_f32_16x16x32_bf16(bf[j], af[i], acc[i][j], 0, 0, 0);
                    else
                        acc[i][j] = __builtin_amdgcn_mfma_f32_16x16x32_bf16(af[i], bf[j], acc[i][j], 0, 0, 0);
                }
        }
        __syncthreads();                     // reads done before next stage overwrites
    }

    if (isV) {
        // normal acc: col=lr (d-col), rows=4lg+{0..3} (tokens) -> pack 4 tokens into vT row
        #pragma unroll
        for (int j = 0; j < BN/32; ++j) {
            int col = (bRow0 & 511) + wco + j*16 + lr;
            float bv = bsV[col];
            int hh = col >> 6, d = col & 63;
            #pragma unroll
            for (int i = 0; i < 4; ++i) {
                int t0 = aRow0 + wlo + i*16 + lg*4;
                int bb = t0 >> 9, tr = t0 & 511;
                unsigned lo = cvt_pk_bf16(acc[i][j][0] + bv, acc[i][j][1] + bv);
                unsigned hi = cvt_pk_bf16(acc[i][j][2] + bv, acc[i][j][3] + bv);
                *(uint2*)(oVT + ((size_t)((bb*HEADS + hh)*EMB + d))*NE + tr) = make_uint2(lo, hi);
            }
        }
    } else {
        // swapped acc: row=...+lr, cols=...+4lg+{0..3} -> one uint2 per (i,j)
        const int sel = (EPI == 4) ? ((bRow0 >> 9) & 1) : 0;
        u16* dst = (EPI == 4) ? (sel ? oK : oQ) : oQ;
        const float* bias = (EPI == 4) ? (sel ? bsK : bsQ) : bsQ;
        const int cb = (EPI == 4) ? (bRow0 & 511) : bRow0;
        const int ldc = (EPI == 4) ? DMODEL : N;
        #pragma unroll
        for (int j = 0; j < BN/32; ++j) {
            int col0 = cb + wco + j*16 + lg*4;
            float4 b4 = *(const float4*)&bias[col0];
            #pragma unroll
            for (int i = 0; i < 4; ++i) {
                int row = aRow0 + wlo + i*16 + lr;
                float v0 = acc[i][j][0] + b4.x, v1 = acc[i][j][1] + b4.y;
                float v2 = acc[i][j][2] + b4.z, v3 = acc[i][j][3] + b4.w;
                if (EPI == 2) { v0 = fmaxf(v0, 0.f); v1 = fmaxf(v1, 0.f);
                                v2 = fmaxf(v2, 0.f); v3 = fmaxf(v3, 0.f); }
                if (EPI == 4 && sel == 0) {
                    const float SCL = 0.18033688011112042f;   // 0.125*log2(e)
                    v0 *= SCL; v1 *= SCL; v2 *= SCL; v3 *= SCL;
                }
                *(uint2*)(dst + (size_t)row*ldc + col0)
                    = make_uint2(cvt_pk_bf16(v0, v1), cvt_pk_bf16(v2, v3));
            }
        }
    }
}

// ---------------- attention (streaming, swapped-operand, permuted-key PV) ----------------
__global__ __launch_bounds__(512, 2) void attn_kernel(
    const u16* __restrict__ Q, const u16* __restrict__ Kb,
    const u16* __restrict__ VT, u16* __restrict__ O)
{
    extern __shared__ char smem[];   // [0,64K) K swz; [64K, 64K+66560) V^T padded
    const int b = blockIdx.x >> 3, h = blockIdx.x & 7;
    const int tid = threadIdx.x, wave = tid >> 6, lane = tid & 63;
    const int lr = lane & 15, lg = lane >> 4, lr7 = lr & 7;

    const int srow = tid >> 3, schunk = tid & 7;
    const int soff = ((schunk ^ (srow & 7)) << 3);
    #pragma unroll
    for (int i = 0; i < 8; ++i)
        GLOAD16(Kb + (size_t)(b*NE + i*64 + srow)*DMODEL + h*EMB + soff,
                (char*)smem + i*8192 + wave*1024);
    #pragma unroll
    for (int i = 0; i < 8; ++i) {
        int row = i*8 + wave;
        GLOAD16(VT + (size_t)((b*HEADS + h)*EMB + row)*NE + lane*8,
                (char*)smem + 65536 + row*1040);
    }

    const int q0 = wave*64;
    v8s qa[4][2];
    #pragma unroll
    for (int ti = 0; ti < 4; ++ti) {
        const u16* qr = Q + (size_t)(b*NE + q0 + ti*16 + lr)*DMODEL + h*EMB;
        qa[ti][0] = *(const v8s*)(qr + lg*8);
        qa[ti][1] = *(const v8s*)(qr + 32 + lg*8);
    }
    __syncthreads();

    f32x4 o[4][4] = {};
    float ssum[4] = {0.f, 0.f, 0.f, 0.f};

    #pragma unroll 1
    for (int c = 0; c < 16; ++c) {
        const char* kr0 = (const char*)smem + ((2*c  )*16 + lr)*128;
        const char* kr1 = (const char*)smem + ((2*c+1)*16 + lr)*128;
        v8s kA0 = *(const v8s*)(kr0 + ((lg ^ lr7) << 4));
        v8s kA1 = *(const v8s*)(kr0 + (((4|lg) ^ lr7) << 4));
        v8s kB0 = *(const v8s*)(kr1 + ((lg ^ lr7) << 4));
        v8s kB1 = *(const v8s*)(kr1 + (((4|lg) ^ lr7) << 4));
        v8s vf[4];
        #pragma unroll
        for (int dt = 0; dt < 4; ++dt) {
            const char* vr = (const char*)smem + 65536 + (dt*16 + lr)*1040 + c*64 + lg*8;
            uint2 lo = *(const uint2*)(vr);
            uint2 hi = *(const uint2*)(vr + 32);
            uint4 u = make_uint4(lo.x, lo.y, hi.x, hi.y);
            vf[dt] = *(v8s*)&u;
        }
        #pragma unroll
        for (int ti = 0; ti < 4; ++ti) {
            f32x4 s0 = {0.f,0.f,0.f,0.f}, s1 = {0.f,0.f,0.f,0.f};
            s0 = __builtin_amdgcn_mfma_f32_16x16x32_bf16(kA0, qa[ti][0], s0, 0, 0, 0);
            s0 = __builtin_amdgcn_mfma_f32_16x16x32_bf16(kA1, qa[ti][1], s0, 0, 0, 0);
            s1 = __builtin_amdgcn_mfma_f32_16x16x32_bf16(kB0, qa[ti][0], s1, 0, 0, 0);
            s1 = __builtin_amdgcn_mfma_f32_16x16x32_bf16(kB1, qa[ti][1], s1, 0, 0, 0);
            float p0 = exp2f(s0[0]), p1 = exp2f(s0[1]), p2 = exp2f(s0[2]), p3 = exp2f(s0[3]);
            float r0 = exp2f(s1[0]), r1 = exp2f(s1[1]), r2 = exp2f(s1[2]), r3 = exp2f(s1[3]);
            ssum[ti] += ((p0 + p1) + (p2 + p3)) + ((r0 + r1) + (r2 + r3));
            unsigned a0 = cvt_pk_bf16(p0, p1), a1 = cvt_pk_bf16(p2, p3);
            unsigned b0 = cvt_pk_bf16(r0, r1), b1 = cvt_pk_bf16(r2, r3);
            uint4 pu = make_uint4(a0, a1, b0, b1);
            v8s pb = *(v8s*)&pu;
            #pragma unroll
            for (int dt = 0; dt < 4; ++dt)
                o[ti][dt] = __builtin_amdgcn_mfma_f32_16x16x32_bf16(vf[dt], pb, o[ti][dt], 0, 0, 0);
        }
    }

    __syncthreads();

    float rinv[4];
    #pragma unroll
    for (int ti = 0; ti < 4; ++ti) {
        float v = ssum[ti];
        v += __shfl_xor(v, 16);
        v += __shfl_xor(v, 32);
        rinv[ti] = 1.f / v;
    }

    char* ow = (char*)smem + wave*10240;
    #pragma unroll
    for (int ti = 0; ti < 4; ++ti) {
        #pragma unroll
        for (int dt = 0; dt < 4; ++dt) {
            unsigned d0 = cvt_pk_bf16(o[ti][dt][0]*rinv[ti], o[ti][dt][1]*rinv[ti]);
            unsigned d1 = cvt_pk_bf16(o[ti][dt][2]*rinv[ti], o[ti][dt][3]*rinv[ti]);
            *(uint2*)(ow + (ti*16 + lr)*160 + dt*32 + lg*8) = make_uint2(d0, d1);
        }
    }
    __asm__ volatile("s_waitcnt lgkmcnt(0)" ::: "memory");
    #pragma unroll
    for (int it = 0; it < 8; ++it) {
        int rr2 = it*8 + (lane >> 3);
        uint4 v = *(const uint4*)(ow + rr2*160 + (lane & 7)*16);
        *(uint4*)(O + (size_t)(b*NE + q0 + rr2)*DMODEL + h*EMB + (lane & 7)*8) = v;
    }
}

// ---------------- residual + layernorm ----------------
template<int MODE>
__global__ __launch_bounds__(256) void add_ln_kernel(
    const u16* __restrict__ a, const float* __restrict__ r32,
    const u16* __restrict__ r16, const float* __restrict__ g,
    const float* __restrict__ be, u16* __restrict__ out16, float* __restrict__ out32)
{
    const int row = blockIdx.x;
    const int t = threadIdx.x;
    const int lane = t & 63, wave = t >> 6;
    float v[2];
    #pragma unroll
    for (int i = 0; i < 2; ++i) {
        int c = t + i*256;
        size_t idx = (size_t)row * DMODEL + c;
        float av = bf2f_bits(a[idx]);
        float rv = (MODE == 0) ? r32[idx] : bf2f_bits(r16[idx]);
        v[i] = av + rv;
    }
    float s = v[0] + v[1];
    float q = v[0]*v[0] + v[1]*v[1];
    #pragma unroll
    for (int d = 1; d < 64; d <<= 1) { s += __shfl_xor(s, d); q += __shfl_xor(q, d); }
    __shared__ float ssum[4], ssq[4];
    if (lane == 0) { ssum[wave] = s; ssq[wave] = q; }
    __syncthreads();
    s = ssum[0] + ssum[1] + ssum[2] + ssum[3];
    q = ssq[0] + ssq[1] + ssq[2] + ssq[3];
    const float mu = s * (1.f / DMODEL);
    const float var = q * (1.f / DMODEL) - mu * mu;
    const float rs = rsqrtf(var + 1e-5f);
    #pragma unroll
    for (int i = 0; i < 2; ++i) {
        int c = t + i*256;
        size_t idx = (size_t)row * DMODEL + c;
        float ov = (v[i] - mu) * rs * g[c] + be[c];
        if (MODE == 0) out16[idx] = f2bf_bits(ov); else out32[idx] = ov;
    }
}

// ---------------- launcher ----------------

extern "C" void kernel_launch(void* const* d_in, const int* in_sizes, int n_in,
                              void* d_out, int out_size, void* d_ws, size_t ws_size,
                              hipStream_t stream)
{
    const float* x   = (const float*)d_in[0];
    const float* Wq  = (const float*)d_in[1];
    const float* bq  = (const float*)d_in[2];
    const float* Wk  = (const float*)d_in[3];
    const float* bk  = (const float*)d_in[4];
    const float* Wv  = (const float*)d_in[5];
    const float* bv  = (const float*)d_in[6];
    const float* W1  = (const float*)d_in[7];
    const float* bf1 = (const float*)d_in[8];
    const float* W2  = (const float*)d_in[9];
    const float* bf2 = (const float*)d_in[10];
    const float* g1  = (const float*)d_in[11];
    const float* be1 = (const float*)d_in[12];
    const float* g2  = (const float*)d_in[13];
    const float* be2 = (const float*)d_in[14];

    char* ws = (char*)d_ws;
    const size_t MB = 1ull << 20;
    const size_t KB = 1024;
    u16* xb    = (u16*)(ws + 0);          // x bf16 (dead after QKV GEMM)
    u16* attnb = (u16*)(ws + 0);          // attention output (aliases xb)
    u16* qb    = (u16*)(ws + 16*MB);      // q (dead after attn)
    u16* f1    = (u16*)(ws + 16*MB);      // ff hidden (aliases qb)
    u16* kb    = (u16*)(ws + 32*MB);      // k (dead after attn)
    u16* ffb   = (u16*)(ws + 32*MB);      // ff output (aliases kb)
    u16* vT    = (u16*)(ws + 48*MB);      // v transposed [b][h][d][ne]
    u16* hb    = (u16*)(ws + 64*MB);      // h = LN1 output
    u16* WqkvT = (u16*)(ws + 80*MB);                 // [1536][512]
    u16* W1T   = (u16*)(ws + 80*MB + 1536*KB);       // [256][512]
    u16* W2T   = (u16*)(ws + 80*MB + 1792*KB);       // [512][256]
    (void)ws_size; (void)in_sizes; (void)n_in; (void)out_size;

    cvt_all_kernel<<<12288, 256, 0, stream>>>(x, xb, Wq, Wk, Wv, W1, W2, WqkvT, W1T, W2T);

    // fused QKV: 6 col-blocks of 256 (Q:0-1, K:2-3 swapped; V:4-5 normal), 128 row-blocks
    gemm_kernel<4, 512, 256><<<768, 256, 0, stream>>>(xb, WqkvT, bq, bk, bv, qb, kb, vT, 1536, 6);

    attn_kernel<<<256, 512, 132096, stream>>>(qb, kb, vT, attnb);

    add_ln_kernel<0><<<MTOK, 256, 0, stream>>>(attnb, x, nullptr, g1, be1, hb, nullptr);

    gemm_kernel<2, 512, 128><<<256, 256, 0, stream>>>(hb, W1T, bf1, bf1, bf1, f1, f1, f1, 256, 2);
    gemm_kernel<0, 256, 256><<<256, 256, 0, stream>>>(f1, W2T, bf2, bf2, bf2, ffb, ffb, ffb, 512, 2);

    add_ln_kernel<1><<<MTOK, 256, 0, stream>>>(ffb, nullptr, hb, g2, be2, nullptr, (float*)d_out);
}

// Round 9
// 160.672 us; speedup vs baseline: 1.2700x; 1.2700x over previous
//
#include <hip/hip_runtime.h>

#define BS 32
#define NE 512
#define DMODEL 512
#define HEADS 8
#define EMB 64
#define FFH 256
#define MTOK (BS*NE)   // 16384

typedef unsigned short u16;
typedef short v8s __attribute__((ext_vector_type(8)));
typedef float f32x4 __attribute__((ext_vector_type(4)));
typedef u16 u16x4 __attribute__((ext_vector_type(4)));

#define GLOAD16(G, L) \
  __builtin_amdgcn_global_load_lds((const __attribute__((address_space(1))) unsigned int*)(G), \
      (__attribute__((address_space(3))) unsigned int*)(L), 16, 0, 0)

static __device__ __forceinline__ unsigned cvt_pk_bf16(float lo, float hi) {
    unsigned r;
    asm("v_cvt_pk_bf16_f32 %0, %1, %2" : "=v"(r) : "v"(lo), "v"(hi));
    return r;
}

static __device__ __forceinline__ u16 f2bf_bits(float f) {
    unsigned u = __float_as_uint(f);
    u += 0x7fffu + ((u >> 16) & 1u);   // round-to-nearest-even
    return (u16)(u >> 16);
}
static __device__ __forceinline__ float bf2f_bits(u16 h) {
    return __uint_as_float(((unsigned)h) << 16);
}

// ---------------- fused conversion kernel ----------------
// x -> xp in MFMA-fragment-packed layout [row16][k8][16][8];
// Wq/Wk/Wv -> Wqkvp packed the same way (row = output col 0..1535);
// W1/W2 -> row-major transposed bf16 (for the LDS-staged FF GEMMs).
__global__ __launch_bounds__(256) void cvt_all_kernel(
    const float* __restrict__ x, u16* __restrict__ xp,
    const float* __restrict__ Wq, const float* __restrict__ Wk, const float* __restrict__ Wv,
    const float* __restrict__ W1, const float* __restrict__ W2,
    u16* __restrict__ Wqkvp, u16* __restrict__ W1T, u16* __restrict__ W2T)
{
    int idx = blockIdx.x * 256 + threadIdx.x;
    if (idx < 2097152) {                      // x: MTOK*DMODEL/4 float4s
        float4 v = ((const float4*)x)[idx];
        int e = idx * 4;
        int row = e >> 9, k = e & 511;
        u16x4 o = { f2bf_bits(v.x), f2bf_bits(v.y), f2bf_bits(v.z), f2bf_bits(v.w) };
        *(u16x4*)(xp + ((size_t)(row >> 4)*64 + (k >> 3))*128 + (row & 15)*8 + (k & 7)) = o;
        return;
    }
    int widx = idx - 2097152;                 // 0 .. 1048575
    if (widx < 786432) {
        int w = widx >> 18, rem = widx & 262143;
        int k = rem >> 9, n = rem & 511;
        const float* src = (w == 0) ? Wq : (w == 1) ? Wk : Wv;
        int np = w*512 + n;
        Wqkvp[((size_t)(np >> 4)*64 + (k >> 3))*128 + (np & 15)*8 + (k & 7)] = f2bf_bits(src[rem]);
    } else if (widx < 917504) {
        int rem = widx - 786432;              // W1: [512][256]
        int k = rem >> 8, n = rem & 255;
        W1T[n*512 + k] = f2bf_bits(W1[rem]);
    } else if (widx < 1048576) {
        int rem = widx - 917504;              // W2: [256][512]
        int k = rem >> 9, n = rem & 511;
        W2T[n*256 + k] = f2bf_bits(W2[rem]);
    }
}

// ---------------- streaming QKV GEMM (no LDS, no barriers) ----------------
// A, B both fragment-packed [blk16][kblk8][16][8]. 128x128 tile, 4 waves (64x64 each).
// K=512 fixed: 16 K-steps, register ping-pong prefetch, 16 MFMA per step.
// SWAP=1: Q/K cols (acc = C^T = mfma(B,A)) -> row-major qb/kb, Q pre-scaled.
// SWAP=0: V cols (normal acc) -> vT [b][h][d][ne] packing.
template<int SWAP>
__global__ __launch_bounds__(256) void qkv_stream_kernel(
    const u16* __restrict__ Ap, const u16* __restrict__ Bp,
    const float* __restrict__ bsQ, const float* __restrict__ bsK, const float* __restrict__ bsV,
    u16* __restrict__ oQ, u16* __restrict__ oK, u16* __restrict__ oVT,
    int NC, int colBase)
{
    const int tid = threadIdx.x, wave = tid >> 6, lane = tid & 63;
    const int lr = lane & 15, lg = lane >> 4;
    const int id = blockIdx.x;
    const int rr = id & 7, qq = id >> 3;
    const int gk = qq / NC, colBlk = qq - gk*NC;
    const int rowBlk = gk*8 + rr;
    const int aRow0 = rowBlk*128, bRow0 = colBase + colBlk*128;
    const int wlo = (wave >> 1)*64, wco = (wave & 1)*64;

    // fragment base pointers (u16 units): frag(i, kstep t) = base + i*8192 + t*512
    const u16* a0 = Ap + ((size_t)((aRow0 + wlo) >> 4)*64 + lg)*128 + lr*8;
    const u16* b0 = Bp + ((size_t)((bRow0 + wco) >> 4)*64 + lg)*128 + lr*8;

    f32x4 acc[4][4] = {};
    v8s afA[4], bfA[4], afB[4], bfB[4];
    #pragma unroll
    for (int i = 0; i < 4; ++i) {
        afA[i] = *(const v8s*)(a0 + i*8192);
        bfA[i] = *(const v8s*)(b0 + i*8192);
    }

    #pragma unroll
    for (int tp = 0; tp < 8; ++tp) {
        #pragma unroll
        for (int i = 0; i < 4; ++i) {
            afB[i] = *(const v8s*)(a0 + (2*tp + 1)*512 + i*8192);
            bfB[i] = *(const v8s*)(b0 + (2*tp + 1)*512 + i*8192);
        }
        #pragma unroll
        for (int i = 0; i < 4; ++i)
            #pragma unroll
            for (int j = 0; j < 4; ++j)
                acc[i][j] = SWAP
                    ? __builtin_amdgcn_mfma_f32_16x16x32_bf16(bfA[j], afA[i], acc[i][j], 0, 0, 0)
                    : __builtin_amdgcn_mfma_f32_16x16x32_bf16(afA[i], bfA[j], acc[i][j], 0, 0, 0);
        if (tp < 7) {
            #pragma unroll
            for (int i = 0; i < 4; ++i) {
                afA[i] = *(const v8s*)(a0 + (2*tp + 2)*512 + i*8192);
                bfA[i] = *(const v8s*)(b0 + (2*tp + 2)*512 + i*8192);
            }
        }
        #pragma unroll
        for (int i = 0; i < 4; ++i)
            #pragma unroll
            for (int j = 0; j < 4; ++j)
                acc[i][j] = SWAP
                    ? __builtin_amdgcn_mfma_f32_16x16x32_bf16(bfB[j], afB[i], acc[i][j], 0, 0, 0)
                    : __builtin_amdgcn_mfma_f32_16x16x32_bf16(afB[i], bfB[j], acc[i][j], 0, 0, 0);
    }

    if (SWAP) {
        // swapped acc: row = ...+lr, cols = ...+4lg+{0..3} -> one uint2 per (i,j)
        const int sel = (bRow0 >> 9) & 1;          // 0 = Q, 1 = K
        u16* dst = sel ? oK : oQ;
        const float* bias = sel ? bsK : bsQ;
        const int cb = bRow0 & 511;
        #pragma unroll
        for (int j = 0; j < 4; ++j) {
            int col0 = cb + wco + j*16 + lg*4;
            float4 b4 = *(const float4*)&bias[col0];
            #pragma unroll
            for (int i = 0; i < 4; ++i) {
                int row = aRow0 + wlo + i*16 + lr;
                float v0 = acc[i][j][0] + b4.x, v1 = acc[i][j][1] + b4.y;
                float v2 = acc[i][j][2] + b4.z, v3 = acc[i][j][3] + b4.w;
                if (sel == 0) {
                    const float SCL = 0.18033688011112042f;   // 0.125*log2(e)
                    v0 *= SCL; v1 *= SCL; v2 *= SCL; v3 *= SCL;
                }
                *(uint2*)(dst + (size_t)row*DMODEL + col0)
                    = make_uint2(cvt_pk_bf16(v0, v1), cvt_pk_bf16(v2, v3));
            }
        }
    } else {
        // normal acc: col = lr (d-col), rows = 4lg+{0..3} (tokens) -> pack into vT row
        #pragma unroll
        for (int j = 0; j < 4; ++j) {
            int col = (bRow0 & 511) + wco + j*16 + lr;
            float bv = bsV[col];
            int hh = col >> 6, d = col & 63;
            #pragma unroll
            for (int i = 0; i < 4; ++i) {
                int t0 = aRow0 + wlo + i*16 + lg*4;
                int bb = t0 >> 9, tr = t0 & 511;
                unsigned lo = cvt_pk_bf16(acc[i][j][0] + bv, acc[i][j][1] + bv);
                unsigned hi = cvt_pk_bf16(acc[i][j][2] + bv, acc[i][j][3] + bv);
                *(uint2*)(oVT + ((size_t)((bb*HEADS + hh)*EMB + d))*NE + tr) = make_uint2(lo, hi);
            }
        }
    }
}

// ---------------- FF GEMM: C = A(MxKC) @ BT(NxKC)^T + bias ----------------
// round-7 structure: 128x128 tile, BK=64, double-buffered LDS, one barrier/K-step.
// EPI 0: swapped acc -> row-major uint2 store   EPI 2: same + relu
template<int EPI, int KC>
__global__ __launch_bounds__(256, 2) void gemm_kernel(
    const u16* __restrict__ A, const u16* __restrict__ BT,
    const float* __restrict__ bias, u16* __restrict__ oC,
    int N, int NC)
{
    __shared__ u16 Ab[2][128*64];
    __shared__ u16 Bb[2][128*64];
    const int tid = threadIdx.x;
    const int wave = tid >> 6, lane = tid & 63;
    const int lr = lane & 15, lg = lane >> 4, lr7 = lr & 7;
    const int id = blockIdx.x;
    const int rr = id & 7, qq = id >> 3;
    const int gk = qq / NC, colBlk = qq - gk*NC;
    const int rowBlk = gk*8 + rr;
    const int aRow0 = rowBlk*128, bRow0 = colBlk*128;
    const int wlo = (wave >> 1)*64, wco = (wave & 1)*64;
    const int srow = tid >> 3, schunk = tid & 7;
    const int soff = ((schunk ^ (srow & 7)) << 3);

    auto stage = [&](int bsel, int k0) {
        #pragma unroll
        for (int i = 0; i < 4; ++i) {
            int row = i*32 + srow;
            GLOAD16(A  + (size_t)(aRow0 + row)*KC + k0 + soff, (char*)&Ab[bsel][0] + i*4096 + wave*1024);
            GLOAD16(BT + (size_t)(bRow0 + row)*KC + k0 + soff, (char*)&Bb[bsel][0] + i*4096 + wave*1024);
        }
    };

    stage(0, 0);

    f32x4 acc[4][4] = {};
    constexpr int NT = KC / 64;
    #pragma unroll
    for (int t = 0; t < NT; ++t) {
        const int cur = t & 1;
        asm volatile("s_waitcnt vmcnt(0)" ::: "memory");
        __builtin_amdgcn_s_barrier();
        if (t + 1 < NT) stage(cur ^ 1, (t + 1) * 64);
        #pragma unroll
        for (int kk = 0; kk < 2; ++kk) {
            v8s af[4], bf[4];
            #pragma unroll
            for (int i = 0; i < 4; ++i) {
                af[i] = *(const v8s*)((const char*)&Ab[cur][0] + (wlo + i*16 + lr)*128 + ((((kk<<2)|lg) ^ lr7) << 4));
                bf[i] = *(const v8s*)((const char*)&Bb[cur][0] + (wco + i*16 + lr)*128 + ((((kk<<2)|lg) ^ lr7) << 4));
            }
            #pragma unroll
            for (int i = 0; i < 4; ++i)
                #pragma unroll
                for (int j = 0; j < 4; ++j)
                    acc[i][j] = __builtin_amdgcn_mfma_f32_16x16x32_bf16(bf[j], af[i], acc[i][j], 0, 0, 0);
        }
    }

    #pragma unroll
    for (int j = 0; j < 4; ++j) {
        int col0 = bRow0 + wco + j*16 + lg*4;
        float4 b4 = *(const float4*)&bias[col0];
        #pragma unroll
        for (int i = 0; i < 4; ++i) {
            int row = aRow0 + wlo + i*16 + lr;
            float v0 = acc[i][j][0] + b4.x, v1 = acc[i][j][1] + b4.y;
            float v2 = acc[i][j][2] + b4.z, v3 = acc[i][j][3] + b4.w;
            if (EPI == 2) { v0 = fmaxf(v0, 0.f); v1 = fmaxf(v1, 0.f);
                            v2 = fmaxf(v2, 0.f); v3 = fmaxf(v3, 0.f); }
            *(uint2*)(oC + (size_t)row*N + col0)
                = make_uint2(cvt_pk_bf16(v0, v1), cvt_pk_bf16(v2, v3));
        }
    }
}

// ---------------- attention (streaming, swapped-operand, permuted-key PV) ----------------
__global__ __launch_bounds__(512, 2) void attn_kernel(
    const u16* __restrict__ Q, const u16* __restrict__ Kb,
    const u16* __restrict__ VT, u16* __restrict__ O)
{
    extern __shared__ char smem[];   // [0,64K) K swz; [64K, 64K+66560) V^T padded
    const int b = blockIdx.x >> 3, h = blockIdx.x & 7;
    const int tid = threadIdx.x, wave = tid >> 6, lane = tid & 63;
    const int lr = lane & 15, lg = lane >> 4, lr7 = lr & 7;

    const int srow = tid >> 3, schunk = tid & 7;
    const int soff = ((schunk ^ (srow & 7)) << 3);
    #pragma unroll
    for (int i = 0; i < 8; ++i)
        GLOAD16(Kb + (size_t)(b*NE + i*64 + srow)*DMODEL + h*EMB + soff,
                (char*)smem + i*8192 + wave*1024);
    #pragma unroll
    for (int i = 0; i < 8; ++i) {
        int row = i*8 + wave;
        GLOAD16(VT + (size_t)((b*HEADS + h)*EMB + row)*NE + lane*8,
                (char*)smem + 65536 + row*1040);
    }

    const int q0 = wave*64;
    v8s qa[4][2];
    #pragma unroll
    for (int ti = 0; ti < 4; ++ti) {
        const u16* qr = Q + (size_t)(b*NE + q0 + ti*16 + lr)*DMODEL + h*EMB;
        qa[ti][0] = *(const v8s*)(qr + lg*8);
        qa[ti][1] = *(const v8s*)(qr + 32 + lg*8);
    }
    __syncthreads();

    f32x4 o[4][4] = {};
    float ssum[4] = {0.f, 0.f, 0.f, 0.f};

    #pragma unroll 1
    for (int c = 0; c < 16; ++c) {
        const char* kr0 = (const char*)smem + ((2*c  )*16 + lr)*128;
        const char* kr1 = (const char*)smem + ((2*c+1)*16 + lr)*128;
        v8s kA0 = *(const v8s*)(kr0 + ((lg ^ lr7) << 4));
        v8s kA1 = *(const v8s*)(kr0 + (((4|lg) ^ lr7) << 4));
        v8s kB0 = *(const v8s*)(kr1 + ((lg ^ lr7) << 4));
        v8s kB1 = *(const v8s*)(kr1 + (((4|lg) ^ lr7) << 4));
        v8s vf[4];
        #pragma unroll
        for (int dt = 0; dt < 4; ++dt) {
            const char* vr = (const char*)smem + 65536 + (dt*16 + lr)*1040 + c*64 + lg*8;
            uint2 lo = *(const uint2*)(vr);
            uint2 hi = *(const uint2*)(vr + 32);
            uint4 u = make_uint4(lo.x, lo.y, hi.x, hi.y);
            vf[dt] = *(v8s*)&u;
        }
        #pragma unroll
        for (int ti = 0; ti < 4; ++ti) {
            f32x4 s0 = {0.f,0.f,0.f,0.f}, s1 = {0.f,0.f,0.f,0.f};
            s0 = __builtin_amdgcn_mfma_f32_16x16x32_bf16(kA0, qa[ti][0], s0, 0, 0, 0);
            s0 = __builtin_amdgcn_mfma_f32_16x16x32_bf16(kA1, qa[ti][1], s0, 0, 0, 0);
            s1 = __builtin_amdgcn_mfma_f32_16x16x32_bf16(kB0, qa[ti][0], s1, 0, 0, 0);
            s1 = __builtin_amdgcn_mfma_f32_16x16x32_bf16(kB1, qa[ti][1], s1, 0, 0, 0);
            float p0 = exp2f(s0[0]), p1 = exp2f(s0[1]), p2 = exp2f(s0[2]), p3 = exp2f(s0[3]);
            float r0 = exp2f(s1[0]), r1 = exp2f(s1[1]), r2 = exp2f(s1[2]), r3 = exp2f(s1[3]);
            ssum[ti] += ((p0 + p1) + (p2 + p3)) + ((r0 + r1) + (r2 + r3));
            unsigned a0 = cvt_pk_bf16(p0, p1), a1 = cvt_pk_bf16(p2, p3);
            unsigned b0 = cvt_pk_bf16(r0, r1), b1 = cvt_pk_bf16(r2, r3);
            uint4 pu = make_uint4(a0, a1, b0, b1);
            v8s pb = *(v8s*)&pu;
            #pragma unroll
            for (int dt = 0; dt < 4; ++dt)
                o[ti][dt] = __builtin_amdgcn_mfma_f32_16x16x32_bf16(vf[dt], pb, o[ti][dt], 0, 0, 0);
        }
    }

    __syncthreads();

    float rinv[4];
    #pragma unroll
    for (int ti = 0; ti < 4; ++ti) {
        float v = ssum[ti];
        v += __shfl_xor(v, 16);
        v += __shfl_xor(v, 32);
        rinv[ti] = 1.f / v;
    }

    char* ow = (char*)smem + wave*10240;
    #pragma unroll
    for (int ti = 0; ti < 4; ++ti) {
        #pragma unroll
        for (int dt = 0; dt < 4; ++dt) {
            unsigned d0 = cvt_pk_bf16(o[ti][dt][0]*rinv[ti], o[ti][dt][1]*rinv[ti]);
            unsigned d1 = cvt_pk_bf16(o[ti][dt][2]*rinv[ti], o[ti][dt][3]*rinv[ti]);
            *(uint2*)(ow + (ti*16 + lr)*160 + dt*32 + lg*8) = make_uint2(d0, d1);
        }
    }
    __asm__ volatile("s_waitcnt lgkmcnt(0)" ::: "memory");
    #pragma unroll
    for (int it = 0; it < 8; ++it) {
        int rr2 = it*8 + (lane >> 3);
        uint4 v = *(const uint4*)(ow + rr2*160 + (lane & 7)*16);
        *(uint4*)(O + (size_t)(b*NE + q0 + rr2)*DMODEL + h*EMB + (lane & 7)*8) = v;
    }
}

// ---------------- residual + layernorm ----------------
template<int MODE>
__global__ __launch_bounds__(256) void add_ln_kernel(
    const u16* __restrict__ a, const float* __restrict__ r32,
    const u16* __restrict__ r16, const float* __restrict__ g,
    const float* __restrict__ be, u16* __restrict__ out16, float* __restrict__ out32)
{
    const int row = blockIdx.x;
    const int t = threadIdx.x;
    const int lane = t & 63, wave = t >> 6;
    float v[2];
    #pragma unroll
    for (int i = 0; i < 2; ++i) {
        int c = t + i*256;
        size_t idx = (size_t)row * DMODEL + c;
        float av = bf2f_bits(a[idx]);
        float rv = (MODE == 0) ? r32[idx] : bf2f_bits(r16[idx]);
        v[i] = av + rv;
    }
    float s = v[0] + v[1];
    float q = v[0]*v[0] + v[1]*v[1];
    #pragma unroll
    for (int d = 1; d < 64; d <<= 1) { s += __shfl_xor(s, d); q += __shfl_xor(q, d); }
    __shared__ float ssum[4], ssq[4];
    if (lane == 0) { ssum[wave] = s; ssq[wave] = q; }
    __syncthreads();
    s = ssum[0] + ssum[1] + ssum[2] + ssum[3];
    q = ssq[0] + ssq[1] + ssq[2] + ssq[3];
    const float mu = s * (1.f / DMODEL);
    const float var = q * (1.f / DMODEL) - mu * mu;
    const float rs = rsqrtf(var + 1e-5f);
    #pragma unroll
    for (int i = 0; i < 2; ++i) {
        int c = t + i*256;
        size_t idx = (size_t)row * DMODEL + c;
        float ov = (v[i] - mu) * rs * g[c] + be[c];
        if (MODE == 0) out16[idx] = f2bf_bits(ov); else out32[idx] = ov;
    }
}

// ---------------- launcher ----------------

extern "C" void kernel_launch(void* const* d_in, const int* in_sizes, int n_in,
                              void* d_out, int out_size, void* d_ws, size_t ws_size,
                              hipStream_t stream)
{
    const float* x   = (const float*)d_in[0];
    const float* Wq  = (const float*)d_in[1];
    const float* bq  = (const float*)d_in[2];
    const float* Wk  = (const float*)d_in[3];
    const float* bk  = (const float*)d_in[4];
    const float* Wv  = (const float*)d_in[5];
    const float* bv  = (const float*)d_in[6];
    const float* W1  = (const float*)d_in[7];
    const float* bf1 = (const float*)d_in[8];
    const float* W2  = (const float*)d_in[9];
    const float* bf2 = (const float*)d_in[10];
    const float* g1  = (const float*)d_in[11];
    const float* be1 = (const float*)d_in[12];
    const float* g2  = (const float*)d_in[13];
    const float* be2 = (const float*)d_in[14];

    char* ws = (char*)d_ws;
    const size_t MB = 1ull << 20;
    const size_t KB = 1024;
    u16* xp    = (u16*)(ws + 0);          // x packed bf16 (dead after QKV GEMM)
    u16* attnb = (u16*)(ws + 0);          // attention output (aliases xp)
    u16* qb    = (u16*)(ws + 16*MB);      // q (dead after attn)
    u16* f1    = (u16*)(ws + 16*MB);      // ff hidden (aliases qb)
    u16* kb    = (u16*)(ws + 32*MB);      // k (dead after attn)
    u16* ffb   = (u16*)(ws + 32*MB);      // ff output (aliases kb)
    u16* vT    = (u16*)(ws + 48*MB);      // v transposed [b][h][d][ne]
    u16* hb    = (u16*)(ws + 64*MB);      // h = LN1 output
    u16* Wqkvp = (u16*)(ws + 80*MB);                 // packed [96][64][16][8]
    u16* W1T   = (u16*)(ws + 80*MB + 1536*KB);       // [256][512]
    u16* W2T   = (u16*)(ws + 80*MB + 1792*KB);       // [512][256]
    (void)ws_size; (void)in_sizes; (void)n_in; (void)out_size;

    cvt_all_kernel<<<12288, 256, 0, stream>>>(x, xp, Wq, Wk, Wv, W1, W2, Wqkvp, W1T, W2T);

    // streaming fused QKV: QK (8 col-blocks, swapped) + V (4 col-blocks, normal)
    qkv_stream_kernel<1><<<1024, 256, 0, stream>>>(xp, Wqkvp, bq, bk, bv, qb, kb, vT, 8, 0);
    qkv_stream_kernel<0><<<512,  256, 0, stream>>>(xp, Wqkvp, bq, bk, bv, qb, kb, vT, 4, 1024);

    attn_kernel<<<256, 512, 132096, stream>>>(qb, kb, vT, attnb);

    add_ln_kernel<0><<<MTOK, 256, 0, stream>>>(attnb, x, nullptr, g1, be1, hb, nullptr);

    gemm_kernel<2, 512><<<256, 256, 0, stream>>>(hb, W1T, bf1, f1, 256, 2);
    gemm_kernel<0, 256><<<512, 256, 0, stream>>>(f1, W2T, bf2, ffb, 512, 4);

    add_ln_kernel<1><<<MTOK, 256, 0, stream>>>(ffb, nullptr, hb, g2, be2, nullptr, (float*)d_out);
}

// Round 10
// 141.790 us; speedup vs baseline: 1.4391x; 1.1332x over previous
//
#include <hip/hip_runtime.h>

#define BS 32
#define NE 512
#define DMODEL 512
#define HEADS 8
#define EMB 64
#define FFH 256
#define MTOK (BS*NE)   // 16384

typedef unsigned short u16;
typedef short v8s __attribute__((ext_vector_type(8)));
typedef float f32x4 __attribute__((ext_vector_type(4)));
typedef u16 u16x4 __attribute__((ext_vector_type(4)));

#define GLOAD16(G, L) \
  __builtin_amdgcn_global_load_lds((const __attribute__((address_space(1))) unsigned int*)(G), \
      (__attribute__((address_space(3))) unsigned int*)(L), 16, 0, 0)

static __device__ __forceinline__ unsigned cvt_pk_bf16(float lo, float hi) {
    unsigned r;
    asm("v_cvt_pk_bf16_f32 %0, %1, %2" : "=v"(r) : "v"(lo), "v"(hi));
    return r;
}

static __device__ __forceinline__ u16 f2bf_bits(float f) {
    unsigned u = __float_as_uint(f);
    u += 0x7fffu + ((u >> 16) & 1u);   // round-to-nearest-even
    return (u16)(u >> 16);
}
static __device__ __forceinline__ float bf2f_bits(u16 h) {
    return __uint_as_float(((unsigned)h) << 16);
}

// ---------------- fused conversion ----------------
// idx < 2097152: x f32 -> bf16 linear (float4 granules). Above: weights -> transposed bf16.
__global__ __launch_bounds__(256) void cvt_all_kernel(
    const float* __restrict__ x, u16* __restrict__ xb,
    const float* __restrict__ Wq, const float* __restrict__ Wk, const float* __restrict__ Wv,
    const float* __restrict__ W1, const float* __restrict__ W2,
    u16* __restrict__ WqkvT, u16* __restrict__ W1T, u16* __restrict__ W2T)
{
    int idx = blockIdx.x * 256 + threadIdx.x;
    if (idx < 2097152) {
        float4 v = ((const float4*)x)[idx];
        u16x4 o = { f2bf_bits(v.x), f2bf_bits(v.y), f2bf_bits(v.z), f2bf_bits(v.w) };
        ((u16x4*)xb)[idx] = o;
        return;
    }
    int widx = idx - 2097152;                 // 0 .. 1048575
    if (widx < 786432) {
        int w = widx >> 18, rem = widx & 262143;
        int k = rem >> 9, n = rem & 511;
        const float* src = (w == 0) ? Wq : (w == 1) ? Wk : Wv;
        WqkvT[(size_t)(w*512 + n)*512 + k] = f2bf_bits(src[rem]);
    } else if (widx < 917504) {
        int rem = widx - 786432;              // W1: [512][256]
        int k = rem >> 8, n = rem & 255;
        W1T[n*512 + k] = f2bf_bits(W1[rem]);
    } else if (widx < 1048576) {
        int rem = widx - 917504;              // W2: [256][512]
        int k = rem >> 9, n = rem & 511;
        W2T[n*256 + k] = f2bf_bits(W2[rem]);
    }
}

// ---------------- fused QKV GEMM: one dispatch ----------------
// 128x128 tile, 4 waves, BK=64, double-buffered LDS, one barrier per K-step.
// 12 col-panels: 0-3 Q (swapped acc, pre-scaled), 4-7 K (swapped), 8-11 V (normal -> vT).
__global__ __launch_bounds__(256, 2) void qkv_kernel(
    const u16* __restrict__ A, const u16* __restrict__ BT,
    const float* __restrict__ bsQ, const float* __restrict__ bsK, const float* __restrict__ bsV,
    u16* __restrict__ oQ, u16* __restrict__ oK, u16* __restrict__ oVT)
{
    __shared__ u16 Ab[2][128*64];
    __shared__ u16 Bb[2][128*64];
    const int tid = threadIdx.x;
    const int wave = tid >> 6, lane = tid & 63;
    const int lr = lane & 15, lg = lane >> 4, lr7 = lr & 7;
    const int id = blockIdx.x;
    const int rr = id & 7, qq = id >> 3;
    const int gk = qq / 12, colBlk = qq - gk*12;
    const int rowBlk = gk*8 + rr;
    const int aRow0 = rowBlk*128, bRow0 = colBlk*128;
    const int wlo = (wave >> 1)*64, wco = (wave & 1)*64;
    const int srow = tid >> 3, schunk = tid & 7;
    const int soff = ((schunk ^ (srow & 7)) << 3);
    const bool isV = (bRow0 >= 1024);

    auto stage = [&](int bsel, int k0) {
        #pragma unroll
        for (int i = 0; i < 4; ++i) {
            int row = i*32 + srow;
            GLOAD16(A  + (size_t)(aRow0 + row)*512 + k0 + soff, (char*)&Ab[bsel][0] + i*4096 + wave*1024);
            GLOAD16(BT + (size_t)(bRow0 + row)*512 + k0 + soff, (char*)&Bb[bsel][0] + i*4096 + wave*1024);
        }
    };

    stage(0, 0);

    f32x4 acc[4][4] = {};
    #pragma unroll
    for (int t = 0; t < 8; ++t) {
        const int cur = t & 1;
        asm volatile("s_waitcnt vmcnt(0)" ::: "memory");
        __builtin_amdgcn_s_barrier();
        if (t + 1 < 8) stage(cur ^ 1, (t + 1) * 64);
        #pragma unroll
        for (int kk = 0; kk < 2; ++kk) {
            v8s af[4], bf[4];
            #pragma unroll
            for (int i = 0; i < 4; ++i) {
                af[i] = *(const v8s*)((const char*)&Ab[cur][0] + (wlo + i*16 + lr)*128 + ((((kk<<2)|lg) ^ lr7) << 4));
                bf[i] = *(const v8s*)((const char*)&Bb[cur][0] + (wco + i*16 + lr)*128 + ((((kk<<2)|lg) ^ lr7) << 4));
            }
            if (isV) {
                #pragma unroll
                for (int i = 0; i < 4; ++i)
                    #pragma unroll
                    for (int j = 0; j < 4; ++j)
                        acc[i][j] = __builtin_amdgcn_mfma_f32_16x16x32_bf16(af[i], bf[j], acc[i][j], 0, 0, 0);
            } else {
                #pragma unroll
                for (int i = 0; i < 4; ++i)
                    #pragma unroll
                    for (int j = 0; j < 4; ++j)
                        acc[i][j] = __builtin_amdgcn_mfma_f32_16x16x32_bf16(bf[j], af[i], acc[i][j], 0, 0, 0);
            }
        }
    }

    if (isV) {
        // normal acc: col = lr (d-col), rows = 4lg+{0..3} (tokens) -> pack into vT row
        #pragma unroll
        for (int j = 0; j < 4; ++j) {
            int col = (bRow0 & 511) + wco + j*16 + lr;
            float bv = bsV[col];
            int hh = col >> 6, d = col & 63;
            #pragma unroll
            for (int i = 0; i < 4; ++i) {
                int t0 = aRow0 + wlo + i*16 + lg*4;
                int bb = t0 >> 9, tr = t0 & 511;
                unsigned lo = cvt_pk_bf16(acc[i][j][0] + bv, acc[i][j][1] + bv);
                unsigned hi = cvt_pk_bf16(acc[i][j][2] + bv, acc[i][j][3] + bv);
                *(uint2*)(oVT + ((size_t)((bb*HEADS + hh)*EMB + d))*NE + tr) = make_uint2(lo, hi);
            }
        }
    } else {
        const int sel = (bRow0 >> 9) & 1;          // 0 = Q, 1 = K
        u16* dst = sel ? oK : oQ;
        const float* bias = sel ? bsK : bsQ;
        const int cb = bRow0 & 511;
        #pragma unroll
        for (int j = 0; j < 4; ++j) {
            int col0 = cb + wco + j*16 + lg*4;
            float4 b4 = *(const float4*)&bias[col0];
            #pragma unroll
            for (int i = 0; i < 4; ++i) {
                int row = aRow0 + wlo + i*16 + lr;
                float v0 = acc[i][j][0] + b4.x, v1 = acc[i][j][1] + b4.y;
                float v2 = acc[i][j][2] + b4.z, v3 = acc[i][j][3] + b4.w;
                if (sel == 0) {
                    const float SCL = 0.18033688011112042f;   // 0.125*log2(e)
                    v0 *= SCL; v1 *= SCL; v2 *= SCL; v3 *= SCL;
                }
                *(uint2*)(dst + (size_t)row*DMODEL + col0)
                    = make_uint2(cvt_pk_bf16(v0, v1), cvt_pk_bf16(v2, v3));
            }
        }
    }
}

// ---------------- fused FF: f1 = relu(h@W1+b1) in LDS; ffb = f1@W2+b2 ----------------
// block = 64 tokens, 4 waves (wave tile 32 x 128). LDS: B-stage 32K | A-stage 8K | f1 32K.
__global__ __launch_bounds__(256) void ff_fused_kernel(
    const u16* __restrict__ H, const u16* __restrict__ W1T, const float* __restrict__ b1,
    const u16* __restrict__ W2T, const float* __restrict__ b2, u16* __restrict__ oF)
{
    extern __shared__ char smem[];       // 73728 B
    char* BST = smem;                    // 32 KB
    char* AST = smem + 32768;            // 8 KB
    char* F1  = smem + 40960;            // 32 KB: 4 subs x [64 rows][8 chunks]
    const int tid = threadIdx.x;
    const int wave = tid >> 6, lane = tid & 63;
    const int lr = lane & 15, lg = lane >> 4, lr7 = lr & 7;
    const int r0 = blockIdx.x * 64;
    const int wlo = (wave >> 1)*32, wco = (wave & 1)*128;

    // ---- FF1: 64x256 = h(64x512) @ W1 ----
    f32x4 acc[2][8] = {};
    for (int s = 0; s < 8; ++s) {
        int k0 = s*64;
        #pragma unroll
        for (int i = 0; i < 2; ++i) {                    // A: 64x64 tile, 512 slots
            int slot = i*256 + tid;
            int row = slot >> 3, ch = slot & 7;
            GLOAD16(H + (size_t)(r0 + row)*512 + k0 + ((ch ^ (row & 7)) << 3),
                    AST + i*4096 + wave*1024);
        }
        #pragma unroll
        for (int i = 0; i < 8; ++i) {                    // B: 256x64 tile, 2048 slots
            int slot = i*256 + tid;
            int row = slot >> 3, ch = slot & 7;
            GLOAD16(W1T + (size_t)row*512 + k0 + ((ch ^ (row & 7)) << 3),
                    BST + i*4096 + wave*1024);
        }
        __syncthreads();
        #pragma unroll
        for (int kk = 0; kk < 2; ++kk) {
            v8s af[2], bf[8];
            #pragma unroll
            for (int i = 0; i < 2; ++i)
                af[i] = *(const v8s*)(AST + (wlo + i*16 + lr)*128 + ((((kk<<2)|lg) ^ lr7) << 4));
            #pragma unroll
            for (int j = 0; j < 8; ++j)
                bf[j] = *(const v8s*)(BST + (wco + j*16 + lr)*128 + ((((kk<<2)|lg) ^ lr7) << 4));
            #pragma unroll
            for (int i = 0; i < 2; ++i)
                #pragma unroll
                for (int j = 0; j < 8; ++j)
                    acc[i][j] = __builtin_amdgcn_mfma_f32_16x16x32_bf16(bf[j], af[i], acc[i][j], 0, 0, 0);
        }
        __syncthreads();
    }

    // relu + bias, write f1 to LDS (swizzled subtiles of [64][64])
    #pragma unroll
    for (int j = 0; j < 8; ++j) {
        int col0 = wco + j*16 + lg*4;
        float4 b4 = *(const float4*)&b1[col0];
        int cc = col0 >> 3, sub = cc >> 3, cc7 = cc & 7;
        #pragma unroll
        for (int i = 0; i < 2; ++i) {
            int row = wlo + i*16 + lr;
            float v0 = fmaxf(acc[i][j][0] + b4.x, 0.f), v1 = fmaxf(acc[i][j][1] + b4.y, 0.f);
            float v2 = fmaxf(acc[i][j][2] + b4.z, 0.f), v3 = fmaxf(acc[i][j][3] + b4.w, 0.f);
            *(uint2*)(F1 + sub*8192 + row*128 + ((cc7 ^ (row & 7)) << 4) + (lg & 1)*8)
                = make_uint2(cvt_pk_bf16(v0, v1), cvt_pk_bf16(v2, v3));
        }
    }
    __syncthreads();

    // ---- FF2: 64x512 = f1(64x256) @ W2, two 256-col halves ----
    for (int nh = 0; nh < 2; ++nh) {
        f32x4 acc2[2][8] = {};
        for (int s = 0; s < 4; ++s) {
            int k0 = s*64;
            #pragma unroll
            for (int i = 0; i < 8; ++i) {                // B: W2T[nh*256 + 0..255][k0..+63]
                int slot = i*256 + tid;
                int row = slot >> 3, ch = slot & 7;
                GLOAD16(W2T + (size_t)(nh*256 + row)*256 + k0 + ((ch ^ (row & 7)) << 3),
                        BST + i*4096 + wave*1024);
            }
            __syncthreads();
            #pragma unroll
            for (int kk = 0; kk < 2; ++kk) {
                v8s af[2], bf[8];
                #pragma unroll
                for (int i = 0; i < 2; ++i) {
                    int row = wlo + i*16 + lr;
                    af[i] = *(const v8s*)(F1 + s*8192 + row*128 + ((((kk<<2)|lg) ^ lr7) << 4));
                }
                #pragma unroll
                for (int j = 0; j < 8; ++j)
                    bf[j] = *(const v8s*)(BST + (wco + j*16 + lr)*128 + ((((kk<<2)|lg) ^ lr7) << 4));
                #pragma unroll
                for (int i = 0; i < 2; ++i)
                    #pragma unroll
                    for (int j = 0; j < 8; ++j)
                        acc2[i][j] = __builtin_amdgcn_mfma_f32_16x16x32_bf16(bf[j], af[i], acc2[i][j], 0, 0, 0);
            }
            __syncthreads();
        }
        // epilogue: ffb tokens x cols (swapped acc)
        #pragma unroll
        for (int j = 0; j < 8; ++j) {
            int col0 = nh*256 + wco + j*16 + lg*4;
            float4 b4 = *(const float4*)&b2[col0];
            #pragma unroll
            for (int i = 0; i < 2; ++i) {
                int row = r0 + wlo + i*16 + lr;
                float v0 = acc2[i][j][0] + b4.x, v1 = acc2[i][j][1] + b4.y;
                float v2 = acc2[i][j][2] + b4.z, v3 = acc2[i][j][3] + b4.w;
                *(uint2*)(oF + (size_t)row*DMODEL + col0)
                    = make_uint2(cvt_pk_bf16(v0, v1), cvt_pk_bf16(v2, v3));
            }
        }
    }
}

// ---------------- attention (streaming, swapped-operand, permuted-key PV) ----------------
__global__ __launch_bounds__(512, 2) void attn_kernel(
    const u16* __restrict__ Q, const u16* __restrict__ Kb,
    const u16* __restrict__ VT, u16* __restrict__ O)
{
    extern __shared__ char smem[];   // [0,64K) K swz; [64K, 64K+66560) V^T padded
    const int b = blockIdx.x >> 3, h = blockIdx.x & 7;
    const int tid = threadIdx.x, wave = tid >> 6, lane = tid & 63;
    const int lr = lane & 15, lg = lane >> 4, lr7 = lr & 7;

    const int srow = tid >> 3, schunk = tid & 7;
    const int soff = ((schunk ^ (srow & 7)) << 3);
    #pragma unroll
    for (int i = 0; i < 8; ++i)
        GLOAD16(Kb + (size_t)(b*NE + i*64 + srow)*DMODEL + h*EMB + soff,
                (char*)smem + i*8192 + wave*1024);
    #pragma unroll
    for (int i = 0; i < 8; ++i) {
        int row = i*8 + wave;
        GLOAD16(VT + (size_t)((b*HEADS + h)*EMB + row)*NE + lane*8,
                (char*)smem + 65536 + row*1040);
    }

    const int q0 = wave*64;
    v8s qa[4][2];
    #pragma unroll
    for (int ti = 0; ti < 4; ++ti) {
        const u16* qr = Q + (size_t)(b*NE + q0 + ti*16 + lr)*DMODEL + h*EMB;
        qa[ti][0] = *(const v8s*)(qr + lg*8);
        qa[ti][1] = *(const v8s*)(qr + 32 + lg*8);
    }
    __syncthreads();

    f32x4 o[4][4] = {};
    float ssum[4] = {0.f, 0.f, 0.f, 0.f};

    #pragma unroll 1
    for (int c = 0; c < 16; ++c) {
        const char* kr0 = (const char*)smem + ((2*c  )*16 + lr)*128;
        const char* kr1 = (const char*)smem + ((2*c+1)*16 + lr)*128;
        v8s kA0 = *(const v8s*)(kr0 + ((lg ^ lr7) << 4));
        v8s kA1 = *(const v8s*)(kr0 + (((4|lg) ^ lr7) << 4));
        v8s kB0 = *(const v8s*)(kr1 + ((lg ^ lr7) << 4));
        v8s kB1 = *(const v8s*)(kr1 + (((4|lg) ^ lr7) << 4));
        v8s vf[4];
        #pragma unroll
        for (int dt = 0; dt < 4; ++dt) {
            const char* vr = (const char*)smem + 65536 + (dt*16 + lr)*1040 + c*64 + lg*8;
            uint2 lo = *(const uint2*)(vr);
            uint2 hi = *(const uint2*)(vr + 32);
            uint4 u = make_uint4(lo.x, lo.y, hi.x, hi.y);
            vf[dt] = *(v8s*)&u;
        }
        #pragma unroll
        for (int ti = 0; ti < 4; ++ti) {
            f32x4 s0 = {0.f,0.f,0.f,0.f}, s1 = {0.f,0.f,0.f,0.f};
            s0 = __builtin_amdgcn_mfma_f32_16x16x32_bf16(kA0, qa[ti][0], s0, 0, 0, 0);
            s0 = __builtin_amdgcn_mfma_f32_16x16x32_bf16(kA1, qa[ti][1], s0, 0, 0, 0);
            s1 = __builtin_amdgcn_mfma_f32_16x16x32_bf16(kB0, qa[ti][0], s1, 0, 0, 0);
            s1 = __builtin_amdgcn_mfma_f32_16x16x32_bf16(kB1, qa[ti][1], s1, 0, 0, 0);
            float p0 = exp2f(s0[0]), p1 = exp2f(s0[1]), p2 = exp2f(s0[2]), p3 = exp2f(s0[3]);
            float r0 = exp2f(s1[0]), r1 = exp2f(s1[1]), r2 = exp2f(s1[2]), r3 = exp2f(s1[3]);
            ssum[ti] += ((p0 + p1) + (p2 + p3)) + ((r0 + r1) + (r2 + r3));
            unsigned a0 = cvt_pk_bf16(p0, p1), a1 = cvt_pk_bf16(p2, p3);
            unsigned b0 = cvt_pk_bf16(r0, r1), b1 = cvt_pk_bf16(r2, r3);
            uint4 pu = make_uint4(a0, a1, b0, b1);
            v8s pb = *(v8s*)&pu;
            #pragma unroll
            for (int dt = 0; dt < 4; ++dt)
                o[ti][dt] = __builtin_amdgcn_mfma_f32_16x16x32_bf16(vf[dt], pb, o[ti][dt], 0, 0, 0);
        }
    }

    __syncthreads();

    float rinv[4];
    #pragma unroll
    for (int ti = 0; ti < 4; ++ti) {
        float v = ssum[ti];
        v += __shfl_xor(v, 16);
        v += __shfl_xor(v, 32);
        rinv[ti] = 1.f / v;
    }

    char* ow = (char*)smem + wave*10240;
    #pragma unroll
    for (int ti = 0; ti < 4; ++ti) {
        #pragma unroll
        for (int dt = 0; dt < 4; ++dt) {
            unsigned d0 = cvt_pk_bf16(o[ti][dt][0]*rinv[ti], o[ti][dt][1]*rinv[ti]);
            unsigned d1 = cvt_pk_bf16(o[ti][dt][2]*rinv[ti], o[ti][dt][3]*rinv[ti]);
            *(uint2*)(ow + (ti*16 + lr)*160 + dt*32 + lg*8) = make_uint2(d0, d1);
        }
    }
    __asm__ volatile("s_waitcnt lgkmcnt(0)" ::: "memory");
    #pragma unroll
    for (int it = 0; it < 8; ++it) {
        int rr2 = it*8 + (lane >> 3);
        uint4 v = *(const uint4*)(ow + rr2*160 + (lane & 7)*16);
        *(uint4*)(O + (size_t)(b*NE + q0 + rr2)*DMODEL + h*EMB + (lane & 7)*8) = v;
    }
}

// ---------------- residual + layernorm ----------------
template<int MODE>
__global__ __launch_bounds__(256) void add_ln_kernel(
    const u16* __restrict__ a, const float* __restrict__ r32,
    const u16* __restrict__ r16, const float* __restrict__ g,
    const float* __restrict__ be, u16* __restrict__ out16, float* __restrict__ out32)
{
    const int row = blockIdx.x;
    const int t = threadIdx.x;
    const int lane = t & 63, wave = t >> 6;
    float v[2];
    #pragma unroll
    for (int i = 0; i < 2; ++i) {
        int c = t + i*256;
        size_t idx = (size_t)row * DMODEL + c;
        float av = bf2f_bits(a[idx]);
        float rv = (MODE == 0) ? r32[idx] : bf2f_bits(r16[idx]);
        v[i] = av + rv;
    }
    float s = v[0] + v[1];
    float q = v[0]*v[0] + v[1]*v[1];
    #pragma unroll
    for (int d = 1; d < 64; d <<= 1) { s += __shfl_xor(s, d); q += __shfl_xor(q, d); }
    __shared__ float ssum[4], ssq[4];
    if (lane == 0) { ssum[wave] = s; ssq[wave] = q; }
    __syncthreads();
    s = ssum[0] + ssum[1] + ssum[2] + ssum[3];
    q = ssq[0] + ssq[1] + ssq[2] + ssq[3];
    const float mu = s * (1.f / DMODEL);
    const float var = q * (1.f / DMODEL) - mu * mu;
    const float rs = rsqrtf(var + 1e-5f);
    #pragma unroll
    for (int i = 0; i < 2; ++i) {
        int c = t + i*256;
        size_t idx = (size_t)row * DMODEL + c;
        float ov = (v[i] - mu) * rs * g[c] + be[c];
        if (MODE == 0) out16[idx] = f2bf_bits(ov); else out32[idx] = ov;
    }
}

// ---------------- launcher ----------------

extern "C" void kernel_launch(void* const* d_in, const int* in_sizes, int n_in,
                              void* d_out, int out_size, void* d_ws, size_t ws_size,
                              hipStream_t stream)
{
    const float* x   = (const float*)d_in[0];
    const float* Wq  = (const float*)d_in[1];
    const float* bq  = (const float*)d_in[2];
    const float* Wk  = (const float*)d_in[3];
    const float* bk  = (const float*)d_in[4];
    const float* Wv  = (const float*)d_in[5];
    const float* bv  = (const float*)d_in[6];
    const float* W1  = (const float*)d_in[7];
    const float* bf1 = (const float*)d_in[8];
    const float* W2  = (const float*)d_in[9];
    const float* bf2 = (const float*)d_in[10];
    const float* g1  = (const float*)d_in[11];
    const float* be1 = (const float*)d_in[12];
    const float* g2  = (const float*)d_in[13];
    const float* be2 = (const float*)d_in[14];

    char* ws = (char*)d_ws;
    const size_t MB = 1ull << 20;
    const size_t KB = 1024;
    u16* xb    = (u16*)(ws + 0);          // x bf16 (dead after QKV)
    u16* attnb = (u16*)(ws + 0);          // attention output (aliases xb)
    u16* qb    = (u16*)(ws + 16*MB);      // q (dead after attn)
    u16* kb    = (u16*)(ws + 32*MB);      // k (dead after attn)
    u16* ffb   = (u16*)(ws + 32*MB);      // ff output (aliases kb)
    u16* vT    = (u16*)(ws + 48*MB);      // v transposed [b][h][d][ne]
    u16* hb    = (u16*)(ws + 64*MB);      // h = LN1 output
    u16* WqkvT = (u16*)(ws + 80*MB);                 // [1536][512]
    u16* W1T   = (u16*)(ws + 80*MB + 1536*KB);       // [256][512]
    u16* W2T   = (u16*)(ws + 80*MB + 1792*KB);       // [512][256]
    (void)ws_size; (void)in_sizes; (void)n_in; (void)out_size;

    cvt_all_kernel<<<12288, 256, 0, stream>>>(x, xb, Wq, Wk, Wv, W1, W2, WqkvT, W1T, W2T);

    qkv_kernel<<<1536, 256, 0, stream>>>(xb, WqkvT, bq, bk, bv, qb, kb, vT);

    attn_kernel<<<256, 512, 132096, stream>>>(qb, kb, vT, attnb);

    add_ln_kernel<0><<<MTOK, 256, 0, stream>>>(attnb, x, nullptr, g1, be1, hb, nullptr);

    ff_fused_kernel<<<256, 256, 73728, stream>>>(hb, W1T, bf1, W2T, bf2, ffb);

    add_ln_kernel<1><<<MTOK, 256, 0, stream>>>(ffb, nullptr, hb, g2, be2, nullptr, (float*)d_out);
}

// Round 11
// 122.883 us; speedup vs baseline: 1.6605x; 1.1539x over previous
//
#include <hip/hip_runtime.h>

#define BS 32
#define NE 512
#define DMODEL 512
#define HEADS 8
#define EMB 64
#define FFH 256
#define MTOK (BS*NE)   // 16384

typedef unsigned short u16;
typedef short v8s __attribute__((ext_vector_type(8)));
typedef float f32x4 __attribute__((ext_vector_type(4)));
typedef u16 u16x4 __attribute__((ext_vector_type(4)));

#define GLOAD16(G, L) \
  __builtin_amdgcn_global_load_lds((const __attribute__((address_space(1))) unsigned int*)(G), \
      (__attribute__((address_space(3))) unsigned int*)(L), 16, 0, 0)

static __device__ __forceinline__ unsigned cvt_pk_bf16(float lo, float hi) {
    unsigned r;
    asm("v_cvt_pk_bf16_f32 %0, %1, %2" : "=v"(r) : "v"(lo), "v"(hi));
    return r;
}

static __device__ __forceinline__ u16 f2bf_bits(float f) {
    unsigned u = __float_as_uint(f);
    u += 0x7fffu + ((u >> 16) & 1u);   // round-to-nearest-even
    return (u16)(u >> 16);
}
static __device__ __forceinline__ float bf2f_bits(u16 h) {
    return __uint_as_float(((unsigned)h) << 16);
}
static __device__ __forceinline__ float bflo(unsigned w) { return __uint_as_float(w << 16); }
static __device__ __forceinline__ float bfhi(unsigned w) { return __uint_as_float(w & 0xffff0000u); }

// ---------------- fused conversion ----------------
__global__ __launch_bounds__(256) void cvt_all_kernel(
    const float* __restrict__ x, u16* __restrict__ xb,
    const float* __restrict__ Wq, const float* __restrict__ Wk, const float* __restrict__ Wv,
    const float* __restrict__ W1, const float* __restrict__ W2,
    u16* __restrict__ WqkvT, u16* __restrict__ W1T, u16* __restrict__ W2T)
{
    int idx = blockIdx.x * 256 + threadIdx.x;
    if (idx < 2097152) {
        float4 v = ((const float4*)x)[idx];
        u16x4 o = { f2bf_bits(v.x), f2bf_bits(v.y), f2bf_bits(v.z), f2bf_bits(v.w) };
        ((u16x4*)xb)[idx] = o;
        return;
    }
    int widx = idx - 2097152;                 // 0 .. 1048575
    if (widx < 786432) {
        int w = widx >> 18, rem = widx & 262143;
        int k = rem >> 9, n = rem & 511;
        const float* src = (w == 0) ? Wq : (w == 1) ? Wk : Wv;
        WqkvT[(size_t)(w*512 + n)*512 + k] = f2bf_bits(src[rem]);
    } else if (widx < 917504) {
        int rem = widx - 786432;              // W1: [512][256]
        int k = rem >> 8, n = rem & 255;
        W1T[n*512 + k] = f2bf_bits(W1[rem]);
    } else if (widx < 1048576) {
        int rem = widx - 917504;              // W2: [256][512]
        int k = rem >> 9, n = rem & 511;
        W2T[n*256 + k] = f2bf_bits(W2[rem]);
    }
}

// ---------------- fused QKV GEMM (r10, unchanged) ----------------
__global__ __launch_bounds__(256, 2) void qkv_kernel(
    const u16* __restrict__ A, const u16* __restrict__ BT,
    const float* __restrict__ bsQ, const float* __restrict__ bsK, const float* __restrict__ bsV,
    u16* __restrict__ oQ, u16* __restrict__ oK, u16* __restrict__ oVT)
{
    __shared__ u16 Ab[2][128*64];
    __shared__ u16 Bb[2][128*64];
    const int tid = threadIdx.x;
    const int wave = tid >> 6, lane = tid & 63;
    const int lr = lane & 15, lg = lane >> 4, lr7 = lr & 7;
    const int id = blockIdx.x;
    const int rr = id & 7, qq = id >> 3;
    const int gk = qq / 12, colBlk = qq - gk*12;
    const int rowBlk = gk*8 + rr;
    const int aRow0 = rowBlk*128, bRow0 = colBlk*128;
    const int wlo = (wave >> 1)*64, wco = (wave & 1)*64;
    const int srow = tid >> 3, schunk = tid & 7;
    const int soff = ((schunk ^ (srow & 7)) << 3);
    const bool isV = (bRow0 >= 1024);

    auto stage = [&](int bsel, int k0) {
        #pragma unroll
        for (int i = 0; i < 4; ++i) {
            int row = i*32 + srow;
            GLOAD16(A  + (size_t)(aRow0 + row)*512 + k0 + soff, (char*)&Ab[bsel][0] + i*4096 + wave*1024);
            GLOAD16(BT + (size_t)(bRow0 + row)*512 + k0 + soff, (char*)&Bb[bsel][0] + i*4096 + wave*1024);
        }
    };

    stage(0, 0);

    f32x4 acc[4][4] = {};
    #pragma unroll
    for (int t = 0; t < 8; ++t) {
        const int cur = t & 1;
        asm volatile("s_waitcnt vmcnt(0)" ::: "memory");
        __builtin_amdgcn_s_barrier();
        if (t + 1 < 8) stage(cur ^ 1, (t + 1) * 64);
        #pragma unroll
        for (int kk = 0; kk < 2; ++kk) {
            v8s af[4], bf[4];
            #pragma unroll
            for (int i = 0; i < 4; ++i) {
                af[i] = *(const v8s*)((const char*)&Ab[cur][0] + (wlo + i*16 + lr)*128 + ((((kk<<2)|lg) ^ lr7) << 4));
                bf[i] = *(const v8s*)((const char*)&Bb[cur][0] + (wco + i*16 + lr)*128 + ((((kk<<2)|lg) ^ lr7) << 4));
            }
            if (isV) {
                #pragma unroll
                for (int i = 0; i < 4; ++i)
                    #pragma unroll
                    for (int j = 0; j < 4; ++j)
                        acc[i][j] = __builtin_amdgcn_mfma_f32_16x16x32_bf16(af[i], bf[j], acc[i][j], 0, 0, 0);
            } else {
                #pragma unroll
                for (int i = 0; i < 4; ++i)
                    #pragma unroll
                    for (int j = 0; j < 4; ++j)
                        acc[i][j] = __builtin_amdgcn_mfma_f32_16x16x32_bf16(bf[j], af[i], acc[i][j], 0, 0, 0);
            }
        }
    }

    if (isV) {
        #pragma unroll
        for (int j = 0; j < 4; ++j) {
            int col = (bRow0 & 511) + wco + j*16 + lr;
            float bv = bsV[col];
            int hh = col >> 6, d = col & 63;
            #pragma unroll
            for (int i = 0; i < 4; ++i) {
                int t0 = aRow0 + wlo + i*16 + lg*4;
                int bb = t0 >> 9, tr = t0 & 511;
                unsigned lo = cvt_pk_bf16(acc[i][j][0] + bv, acc[i][j][1] + bv);
                unsigned hi = cvt_pk_bf16(acc[i][j][2] + bv, acc[i][j][3] + bv);
                *(uint2*)(oVT + ((size_t)((bb*HEADS + hh)*EMB + d))*NE + tr) = make_uint2(lo, hi);
            }
        }
    } else {
        const int sel = (bRow0 >> 9) & 1;          // 0 = Q, 1 = K
        u16* dst = sel ? oK : oQ;
        const float* bias = sel ? bsK : bsQ;
        const int cb = bRow0 & 511;
        #pragma unroll
        for (int j = 0; j < 4; ++j) {
            int col0 = cb + wco + j*16 + lg*4;
            float4 b4 = *(const float4*)&bias[col0];
            #pragma unroll
            for (int i = 0; i < 4; ++i) {
                int row = aRow0 + wlo + i*16 + lr;
                float v0 = acc[i][j][0] + b4.x, v1 = acc[i][j][1] + b4.y;
                float v2 = acc[i][j][2] + b4.z, v3 = acc[i][j][3] + b4.w;
                if (sel == 0) {
                    const float SCL = 0.18033688011112042f;   // 0.125*log2(e)
                    v0 *= SCL; v1 *= SCL; v2 *= SCL; v3 *= SCL;
                }
                *(uint2*)(dst + (size_t)row*DMODEL + col0)
                    = make_uint2(cvt_pk_bf16(v0, v1), cvt_pk_bf16(v2, v3));
            }
        }
    }
}

// ---------------- attention (r10, unchanged) ----------------
__global__ __launch_bounds__(512, 2) void attn_kernel(
    const u16* __restrict__ Q, const u16* __restrict__ Kb,
    const u16* __restrict__ VT, u16* __restrict__ O)
{
    extern __shared__ char smem[];
    const int b = blockIdx.x >> 3, h = blockIdx.x & 7;
    const int tid = threadIdx.x, wave = tid >> 6, lane = tid & 63;
    const int lr = lane & 15, lg = lane >> 4, lr7 = lr & 7;

    const int srow = tid >> 3, schunk = tid & 7;
    const int soff = ((schunk ^ (srow & 7)) << 3);
    #pragma unroll
    for (int i = 0; i < 8; ++i)
        GLOAD16(Kb + (size_t)(b*NE + i*64 + srow)*DMODEL + h*EMB + soff,
                (char*)smem + i*8192 + wave*1024);
    #pragma unroll
    for (int i = 0; i < 8; ++i) {
        int row = i*8 + wave;
        GLOAD16(VT + (size_t)((b*HEADS + h)*EMB + row)*NE + lane*8,
                (char*)smem + 65536 + row*1040);
    }

    const int q0 = wave*64;
    v8s qa[4][2];
    #pragma unroll
    for (int ti = 0; ti < 4; ++ti) {
        const u16* qr = Q + (size_t)(b*NE + q0 + ti*16 + lr)*DMODEL + h*EMB;
        qa[ti][0] = *(const v8s*)(qr + lg*8);
        qa[ti][1] = *(const v8s*)(qr + 32 + lg*8);
    }
    __syncthreads();

    f32x4 o[4][4] = {};
    float ssum[4] = {0.f, 0.f, 0.f, 0.f};

    #pragma unroll 1
    for (int c = 0; c < 16; ++c) {
        const char* kr0 = (const char*)smem + ((2*c  )*16 + lr)*128;
        const char* kr1 = (const char*)smem + ((2*c+1)*16 + lr)*128;
        v8s kA0 = *(const v8s*)(kr0 + ((lg ^ lr7) << 4));
        v8s kA1 = *(const v8s*)(kr0 + (((4|lg) ^ lr7) << 4));
        v8s kB0 = *(const v8s*)(kr1 + ((lg ^ lr7) << 4));
        v8s kB1 = *(const v8s*)(kr1 + (((4|lg) ^ lr7) << 4));
        v8s vf[4];
        #pragma unroll
        for (int dt = 0; dt < 4; ++dt) {
            const char* vr = (const char*)smem + 65536 + (dt*16 + lr)*1040 + c*64 + lg*8;
            uint2 lo = *(const uint2*)(vr);
            uint2 hi = *(const uint2*)(vr + 32);
            uint4 u = make_uint4(lo.x, lo.y, hi.x, hi.y);
            vf[dt] = *(v8s*)&u;
        }
        #pragma unroll
        for (int ti = 0; ti < 4; ++ti) {
            f32x4 s0 = {0.f,0.f,0.f,0.f}, s1 = {0.f,0.f,0.f,0.f};
            s0 = __builtin_amdgcn_mfma_f32_16x16x32_bf16(kA0, qa[ti][0], s0, 0, 0, 0);
            s0 = __builtin_amdgcn_mfma_f32_16x16x32_bf16(kA1, qa[ti][1], s0, 0, 0, 0);
            s1 = __builtin_amdgcn_mfma_f32_16x16x32_bf16(kB0, qa[ti][0], s1, 0, 0, 0);
            s1 = __builtin_amdgcn_mfma_f32_16x16x32_bf16(kB1, qa[ti][1], s1, 0, 0, 0);
            float p0 = exp2f(s0[0]), p1 = exp2f(s0[1]), p2 = exp2f(s0[2]), p3 = exp2f(s0[3]);
            float r0 = exp2f(s1[0]), r1 = exp2f(s1[1]), r2 = exp2f(s1[2]), r3 = exp2f(s1[3]);
            ssum[ti] += ((p0 + p1) + (p2 + p3)) + ((r0 + r1) + (r2 + r3));
            unsigned a0 = cvt_pk_bf16(p0, p1), a1 = cvt_pk_bf16(p2, p3);
            unsigned b0 = cvt_pk_bf16(r0, r1), b1 = cvt_pk_bf16(r2, r3);
            uint4 pu = make_uint4(a0, a1, b0, b1);
            v8s pb = *(v8s*)&pu;
            #pragma unroll
            for (int dt = 0; dt < 4; ++dt)
                o[ti][dt] = __builtin_amdgcn_mfma_f32_16x16x32_bf16(vf[dt], pb, o[ti][dt], 0, 0, 0);
        }
    }

    __syncthreads();

    float rinv[4];
    #pragma unroll
    for (int ti = 0; ti < 4; ++ti) {
        float v = ssum[ti];
        v += __shfl_xor(v, 16);
        v += __shfl_xor(v, 32);
        rinv[ti] = 1.f / v;
    }

    char* ow = (char*)smem + wave*10240;
    #pragma unroll
    for (int ti = 0; ti < 4; ++ti) {
        #pragma unroll
        for (int dt = 0; dt < 4; ++dt) {
            unsigned d0 = cvt_pk_bf16(o[ti][dt][0]*rinv[ti], o[ti][dt][1]*rinv[ti]);
            unsigned d1 = cvt_pk_bf16(o[ti][dt][2]*rinv[ti], o[ti][dt][3]*rinv[ti]);
            *(uint2*)(ow + (ti*16 + lr)*160 + dt*32 + lg*8) = make_uint2(d0, d1);
        }
    }
    __asm__ volatile("s_waitcnt lgkmcnt(0)" ::: "memory");
    #pragma unroll
    for (int it = 0; it < 8; ++it) {
        int rr2 = it*8 + (lane >> 3);
        uint4 v = *(const uint4*)(ow + rr2*160 + (lane & 7)*16);
        *(uint4*)(O + (size_t)(b*NE + q0 + rr2)*DMODEL + h*EMB + (lane & 7)*8) = v;
    }
}

// ---------------- grand fused LN1 + FF1 + relu + FF2 + residual + LN2 ----------------
// block = 64 tokens, 512 threads / 8 waves. LDS: H 64K | F1 32K | BST 32K | partials 1K.
// h kept in LDS: FF1 A-operand AND LN2 residual. Out = f32 d_out.
__global__ __launch_bounds__(512) void ffln_kernel(
    const u16* __restrict__ At, const float* __restrict__ x,
    const float* __restrict__ g1, const float* __restrict__ be1,
    const u16* __restrict__ W1T, const float* __restrict__ b1,
    const u16* __restrict__ W2T, const float* __restrict__ b2,
    const float* __restrict__ g2, const float* __restrict__ be2,
    float* __restrict__ out)
{
    extern __shared__ char smem[];
    char* H   = smem;              // [64 rows][512B], chunk16 ^ (row&7)
    char* F1  = smem + 65536;      // [64 rows][512B]... F1 row = 256 cols = 512B, 32 chunks
    char* BST = smem + 98304;      // 32KB weight staging tile [256][64k]
    float* Ps = (float*)(smem + 131072);   // [64][2] sum partials
    float* Pq = Ps + 128;                  // [64][2] sq partials

    const int tid = threadIdx.x, wave = tid >> 6, lane = tid & 63;
    const int lr = lane & 15, lg = lane >> 4, lr7 = lr & 7;
    const int r0 = blockIdx.x * 64;

    // ---- LN1: wave handles 8 rows; lane covers cols lane*8..+7 ----
    #pragma unroll
    for (int it = 0; it < 8; ++it) {
        int r = wave*8 + it;
        const u16* arow = At + (size_t)(r0 + r)*512 + lane*8;
        const float* xrow = x + (size_t)(r0 + r)*512 + lane*8;
        uint4 av = *(const uint4*)arow;
        float4 x0 = *(const float4*)xrow;
        float4 x1 = *(const float4*)(xrow + 4);
        float v0 = bflo(av.x) + x0.x, v1 = bfhi(av.x) + x0.y;
        float v2 = bflo(av.y) + x0.z, v3 = bfhi(av.y) + x0.w;
        float v4 = bflo(av.z) + x1.x, v5 = bfhi(av.z) + x1.y;
        float v6 = bflo(av.w) + x1.z, v7 = bfhi(av.w) + x1.w;
        float s = ((v0+v1)+(v2+v3)) + ((v4+v5)+(v6+v7));
        float q = ((v0*v0+v1*v1)+(v2*v2+v3*v3)) + ((v4*v4+v5*v5)+(v6*v6+v7*v7));
        #pragma unroll
        for (int d = 1; d < 64; d <<= 1) { s += __shfl_xor(s, d); q += __shfl_xor(q, d); }
        float mu = s * (1.f/512.f);
        float rs = rsqrtf(q * (1.f/512.f) - mu*mu + 1e-5f);
        float4 gA = *(const float4*)(g1 + lane*8), gB = *(const float4*)(g1 + lane*8 + 4);
        float4 eA = *(const float4*)(be1 + lane*8), eB = *(const float4*)(be1 + lane*8 + 4);
        float h0 = (v0-mu)*rs*gA.x + eA.x, h1 = (v1-mu)*rs*gA.y + eA.y;
        float h2 = (v2-mu)*rs*gA.z + eA.z, h3 = (v3-mu)*rs*gA.w + eA.w;
        float h4 = (v4-mu)*rs*gB.x + eB.x, h5 = (v5-mu)*rs*gB.y + eB.y;
        float h6 = (v6-mu)*rs*gB.z + eB.z, h7 = (v7-mu)*rs*gB.w + eB.w;
        uint4 hw = make_uint4(cvt_pk_bf16(h0,h1), cvt_pk_bf16(h2,h3),
                              cvt_pk_bf16(h4,h5), cvt_pk_bf16(h6,h7));
        *(uint4*)(H + r*1024 + ((lane ^ (r & 7)) << 4)) = hw;
    }
    __syncthreads();

    // ---- FF1: 64x256 = h @ W1, 8 waves, wave tile 16 rows x 128 cols ----
    const int wr = (wave & 3)*16, wcB = (wave >> 2)*128;
    f32x4 acc1[8] = {};
    for (int s8 = 0; s8 < 8; ++s8) {
        int k0 = s8*64;
        #pragma unroll
        for (int i = 0; i < 4; ++i) {                 // W1T tile [256][64]
            int slot = i*512 + tid;
            int row = slot >> 3, ch = slot & 7;
            GLOAD16(W1T + (size_t)row*512 + k0 + ((ch ^ (row & 7)) << 3),
                    BST + i*8192 + wave*1024);
        }
        __syncthreads();
        #pragma unroll
        for (int kk = 0; kk < 2; ++kk) {
            v8s af = *(const v8s*)(H + (wr + lr)*1024 + ((s8*8 + ((kk*4 + lg) ^ lr7)) << 4));
            v8s bf[8];
            #pragma unroll
            for (int j = 0; j < 8; ++j)
                bf[j] = *(const v8s*)(BST + (wcB + j*16 + lr)*128 + ((((kk<<2)|lg) ^ lr7) << 4));
            #pragma unroll
            for (int j = 0; j < 8; ++j)
                acc1[j] = __builtin_amdgcn_mfma_f32_16x16x32_bf16(bf[j], af, acc1[j], 0, 0, 0);
        }
        __syncthreads();
    }

    // relu + bias -> F1 (swizzled)
    {
        int row = wr + lr;
        #pragma unroll
        for (int j = 0; j < 8; ++j) {
            int col0 = wcB + j*16 + lg*4;
            float4 b4 = *(const float4*)(b1 + col0);
            float v0 = fmaxf(acc1[j][0] + b4.x, 0.f), v1 = fmaxf(acc1[j][1] + b4.y, 0.f);
            float v2 = fmaxf(acc1[j][2] + b4.z, 0.f), v3 = fmaxf(acc1[j][3] + b4.w, 0.f);
            *(uint2*)(F1 + row*512 + (((col0 >> 3) ^ (row & 7)) << 4) + (col0 & 7)*2)
                = make_uint2(cvt_pk_bf16(v0, v1), cvt_pk_bf16(v2, v3));
        }
    }
    __syncthreads();

    // ---- FF2: 64x512 = f1 @ W2, two 256-col halves ----
    f32x4 acc2[2][8] = {};
    #pragma unroll
    for (int nh = 0; nh < 2; ++nh) {
        for (int s4 = 0; s4 < 4; ++s4) {
            int k0 = s4*64;
            #pragma unroll
            for (int i = 0; i < 4; ++i) {             // W2T tile [256][64] (half nh)
                int slot = i*512 + tid;
                int row = slot >> 3, ch = slot & 7;
                GLOAD16(W2T + (size_t)(nh*256 + row)*256 + k0 + ((ch ^ (row & 7)) << 3),
                        BST + i*8192 + wave*1024);
            }
            __syncthreads();
            #pragma unroll
            for (int kk = 0; kk < 2; ++kk) {
                v8s af = *(const v8s*)(F1 + (wr + lr)*512 + ((s4*8 + ((kk*4 + lg) ^ lr7)) << 4));
                v8s bf[8];
                #pragma unroll
                for (int j = 0; j < 8; ++j)
                    bf[j] = *(const v8s*)(BST + (wcB + j*16 + lr)*128 + ((((kk<<2)|lg) ^ lr7) << 4));
                #pragma unroll
                for (int j = 0; j < 8; ++j)
                    acc2[nh][j] = __builtin_amdgcn_mfma_f32_16x16x32_bf16(bf[j], af, acc2[nh][j], 0, 0, 0);
            }
            __syncthreads();
        }
    }

    // ---- bias + residual(h) + LN2 stats (each lane owns ONE token row) ----
    const int row = wr + lr;
    float s = 0.f, q = 0.f;
    #pragma unroll
    for (int nh = 0; nh < 2; ++nh) {
        #pragma unroll
        for (int j = 0; j < 8; ++j) {
            int col0 = nh*256 + wcB + j*16 + lg*4;
            float4 b4 = *(const float4*)(b2 + col0);
            uint2 hh = *(const uint2*)(H + row*1024 + ((((col0 & 511) >> 3) ^ (row & 7)) << 4) + (col0 & 7)*2);
            f32x4 a = acc2[nh][j];
            a[0] += b4.x + bflo(hh.x); a[1] += b4.y + bfhi(hh.x);
            a[2] += b4.z + bflo(hh.y); a[3] += b4.w + bfhi(hh.y);
            acc2[nh][j] = a;
            s += (a[0]+a[1]) + (a[2]+a[3]);
            q += (a[0]*a[0]+a[1]*a[1]) + (a[2]*a[2]+a[3]*a[3]);
        }
    }
    s += __shfl_xor(s, 16); s += __shfl_xor(s, 32);   // reduce over lg (same row)
    q += __shfl_xor(q, 16); q += __shfl_xor(q, 32);
    if (lg == 0) { Ps[row*2 + (wave >> 2)] = s; Pq[row*2 + (wave >> 2)] = q; }
    __syncthreads();
    float st = Ps[row*2] + Ps[row*2 + 1];
    float qt = Pq[row*2] + Pq[row*2 + 1];
    float mu = st * (1.f/512.f);
    float rs = rsqrtf(qt * (1.f/512.f) - mu*mu + 1e-5f);

    #pragma unroll
    for (int nh = 0; nh < 2; ++nh) {
        #pragma unroll
        for (int j = 0; j < 8; ++j) {
            int col0 = nh*256 + wcB + j*16 + lg*4;
            float4 gg = *(const float4*)(g2 + col0);
            float4 ee = *(const float4*)(be2 + col0);
            f32x4 a = acc2[nh][j];
            float4 o;
            o.x = (a[0]-mu)*rs*gg.x + ee.x;
            o.y = (a[1]-mu)*rs*gg.y + ee.y;
            o.z = (a[2]-mu)*rs*gg.z + ee.z;
            o.w = (a[3]-mu)*rs*gg.w + ee.w;
            *(float4*)(out + (size_t)(r0 + row)*512 + col0) = o;
        }
    }
}

// ---------------- launcher ----------------

extern "C" void kernel_launch(void* const* d_in, const int* in_sizes, int n_in,
                              void* d_out, int out_size, void* d_ws, size_t ws_size,
                              hipStream_t stream)
{
    const float* x   = (const float*)d_in[0];
    const float* Wq  = (const float*)d_in[1];
    const float* bq  = (const float*)d_in[2];
    const float* Wk  = (const float*)d_in[3];
    const float* bk  = (const float*)d_in[4];
    const float* Wv  = (const float*)d_in[5];
    const float* bv  = (const float*)d_in[6];
    const float* W1  = (const float*)d_in[7];
    const float* bf1 = (const float*)d_in[8];
    const float* W2  = (const float*)d_in[9];
    const float* bf2 = (const float*)d_in[10];
    const float* g1  = (const float*)d_in[11];
    const float* be1 = (const float*)d_in[12];
    const float* g2  = (const float*)d_in[13];
    const float* be2 = (const float*)d_in[14];

    char* ws = (char*)d_ws;
    const size_t MB = 1ull << 20;
    const size_t KB = 1024;
    u16* xb    = (u16*)(ws + 0);          // x bf16 (dead after QKV)
    u16* attnb = (u16*)(ws + 0);          // attention output (aliases xb)
    u16* qb    = (u16*)(ws + 16*MB);
    u16* kb    = (u16*)(ws + 32*MB);
    u16* vT    = (u16*)(ws + 48*MB);      // v transposed [b][h][d][ne]
    u16* WqkvT = (u16*)(ws + 80*MB);                 // [1536][512]
    u16* W1T   = (u16*)(ws + 80*MB + 1536*KB);       // [256][512]
    u16* W2T   = (u16*)(ws + 80*MB + 1792*KB);       // [512][256]
    (void)ws_size; (void)in_sizes; (void)n_in; (void)out_size;

    cvt_all_kernel<<<12288, 256, 0, stream>>>(x, xb, Wq, Wk, Wv, W1, W2, WqkvT, W1T, W2T);

    qkv_kernel<<<1536, 256, 0, stream>>>(xb, WqkvT, bq, bk, bv, qb, kb, vT);

    attn_kernel<<<256, 512, 132096, stream>>>(qb, kb, vT, attnb);

    ffln_kernel<<<256, 512, 132096, stream>>>(attnb, x, g1, be1, W1T, bf1, W2T, bf2,
                                              g2, be2, (float*)d_out);
}